// Round 1
// baseline (339.787 us; speedup 1.0000x reference)
//
#include <hip/hip_runtime.h>
#include <cstddef>

// Sizes
#define VOCAB  50000
#define INPUT  512
#define HIDDEN 1024
#define BATCH  64
#define MAXLEN 256

typedef float  f32x4 __attribute__((ext_vector_type(4)));
typedef __bf16 bf16x8 __attribute__((ext_vector_type(8)));

__device__ __forceinline__ bf16x8 cvt8(float4 a, float4 b) {
    bf16x8 r;
    r[0] = (__bf16)a.x; r[1] = (__bf16)a.y; r[2] = (__bf16)a.z; r[3] = (__bf16)a.w;
    r[4] = (__bf16)b.x; r[5] = (__bf16)b.y; r[6] = (__bf16)b.z; r[7] = (__bf16)b.w;
    return r;
}

// u2[k] = sum_h v[h] * attn_W[h, HIDDEN + k]   (the enc-half of attn_W folded with v)
__global__ void k_u2(const float* __restrict__ attn_W, const float* __restrict__ v,
                     float* __restrict__ u2) {
    int k = blockIdx.x * 256 + threadIdx.x;     // 0..1023
    float acc = 0.f;
    for (int h = 0; h < HIDDEN; ++h)
        acc += v[h] * attn_W[(size_t)h * (2 * HIDDEN) + HIDDEN + k];
    u2[k] = acc;
}

// scores[b,t] = dot(enc[t,b,:], u2)  — one wave per (t,b) row
__global__ void k_scores(const float* __restrict__ enc, const float* __restrict__ u2,
                         float* __restrict__ scores) {
    int wid = threadIdx.x >> 6, lane = threadIdx.x & 63;
    int p = blockIdx.x * 4 + wid;               // p = t*BATCH + b, 0..16383
    const float* row = enc + (size_t)p * HIDDEN;
    float acc = 0.f;
#pragma unroll
    for (int i = 0; i < 4; ++i) {
        float4 e = *(const float4*)(row + lane * 4 + i * 256);
        float4 u = *(const float4*)(u2  + lane * 4 + i * 256);
        acc += e.x * u.x + e.y * u.y + e.z * u.z + e.w * u.w;
    }
#pragma unroll
    for (int off = 32; off; off >>= 1) acc += __shfl_down(acc, off, 64);
    if (lane == 0) {
        int b = p & 63, t = p >> 6;
        scores[b * MAXLEN + t] = acc;
    }
}

// softmax over t (256) per batch row
__global__ void k_softmax(const float* __restrict__ scores, float* __restrict__ attn) {
    int b = blockIdx.x, t = threadIdx.x;
    __shared__ float red[256];
    float s = scores[b * MAXLEN + t];
    red[t] = s; __syncthreads();
    for (int off = 128; off; off >>= 1) { if (t < off) red[t] = fmaxf(red[t], red[t + off]); __syncthreads(); }
    float m = red[0]; __syncthreads();
    float e = expf(s - m);
    red[t] = e; __syncthreads();
    for (int off = 128; off; off >>= 1) { if (t < off) red[t] += red[t + off]; __syncthreads(); }
    attn[b * MAXLEN + t] = e * (1.f / red[0]);
}

// context[b,h] = sum_t attn[b,t] * enc[t,b,h]  — block per b, thread per 4 h
__global__ void k_context(const float* __restrict__ enc, const float* __restrict__ attn,
                          float* __restrict__ context) {
    int b = blockIdx.x, tid = threadIdx.x;
    __shared__ float a[256];
    a[tid] = attn[b * MAXLEN + tid];
    __syncthreads();
    int h0 = tid * 4;
    float4 acc = {0.f, 0.f, 0.f, 0.f};
    for (int t = 0; t < MAXLEN; ++t) {
        float4 e = *(const float4*)(enc + ((size_t)(t * BATCH + b)) * HIDDEN + h0);
        float w = a[t];
        acc.x += w * e.x; acc.y += w * e.y; acc.z += w * e.z; acc.w += w * e.w;
    }
    *(float4*)(context + b * HIDDEN + h0) = acc;
}

// Pack bf16 activation buffers: x_bf = [emb | context] (64x1536), hid_bf (64x1024),
// y_bf[:,1024:2048] = context (y_bf[:,0:1024] filled later by k_combine with h_new)
__global__ void k_pack(const int* __restrict__ last_output, const float* __restrict__ embedding,
                       const float* __restrict__ context, const float* __restrict__ hid,
                       __bf16* __restrict__ x_bf, __bf16* __restrict__ hid_bf,
                       __bf16* __restrict__ y_bf) {
    int idx = blockIdx.x * 256 + threadIdx.x;   // 64*2560 total
    int b = idx / 2560, k = idx % 2560;
    if (k < INPUT) {
        float v = embedding[(size_t)last_output[b] * INPUT + k];
        x_bf[b * 1536 + k] = (__bf16)v;
    } else if (k < 1536) {
        float v = context[b * HIDDEN + (k - INPUT)];
        x_bf[b * 1536 + k] = (__bf16)v;
        y_bf[b * 2048 + (k - INPUT) + HIDDEN] = (__bf16)v;
    } else {
        float v = hid[b * HIDDEN + (k - 1536)];
        hid_bf[b * HIDDEN + (k - 1536)] = (__bf16)v;
    }
}

// Generic small-M GEMM: out[64,N] = A_bf16[64,K] @ W_f32[N,K]^T + bias.
// One block per 16-col tile of N; 4 waves split K (K%128==0); LDS reduce.
// MFMA 16x16x32 bf16; same (lanegroup,elem)->k mapping for A and B fragments, so any
// hardware k-permutation cancels. D layout: col=lane&15, row=(lane>>4)*4+reg (m89-verified).
__global__ __launch_bounds__(256) void k_gemm(const float* __restrict__ W,
                                              const float* __restrict__ bias,
                                              const __bf16* __restrict__ A,
                                              float* __restrict__ out,
                                              int N, int K) {
    int tid = threadIdx.x;
    int wid = tid >> 6, lane = tid & 63;
    int jt = blockIdx.x;
    int j  = jt * 16 + (lane & 15);
    int kg = (lane >> 4) * 8;
    int kchunk = K >> 2;
    int kbeg = wid * kchunk, kend = kbeg + kchunk;
    const float*  wrow = W + (size_t)j * K;
    const __bf16* arow = A + (size_t)(lane & 15) * K;
    f32x4 acc[4] = {};
    for (int k0 = kbeg; k0 < kend; k0 += 32) {
        int kk = k0 + kg;
        float4 w0 = *(const float4*)(wrow + kk);
        float4 w1 = *(const float4*)(wrow + kk + 4);
        bf16x8 bw = cvt8(w0, w1);
#pragma unroll
        for (int mt = 0; mt < 4; ++mt) {
            bf16x8 a = *(const bf16x8*)(arow + (size_t)mt * 16 * K + kk);
            acc[mt] = __builtin_amdgcn_mfma_f32_16x16x32_bf16(a, bw, acc[mt], 0, 0, 0);
        }
    }
    __shared__ float lds[4][1024];
#pragma unroll
    for (int mt = 0; mt < 4; ++mt)
#pragma unroll
        for (int r = 0; r < 4; ++r) {
            int m = mt * 16 + (lane >> 4) * 4 + r;
            lds[wid][m * 16 + (lane & 15)] = acc[mt][r];
        }
    __syncthreads();
#pragma unroll
    for (int o = tid; o < 1024; o += 256) {
        float s = lds[0][o] + lds[1][o] + lds[2][o] + lds[3][o];
        int m = o >> 4, jl = o & 15;
        int jj = jt * 16 + jl;
        out[(size_t)m * N + jj] = s + bias[jj];
    }
}

// GRU combine: h_new = (1-z)*n + z*h_prev;  writes f32 h_new to d_out tail and bf16 to y_bf[:,0:1024]
__global__ void k_combine(const float* __restrict__ Gi, const float* __restrict__ Gh,
                          const float* __restrict__ hid, float* __restrict__ hnew_out,
                          __bf16* __restrict__ y_bf) {
    int idx = blockIdx.x * 256 + threadIdx.x;   // 64*1024
    int b = idx >> 10, h = idx & 1023;
    const float* gi = Gi + (size_t)b * 3072;
    const float* gh = Gh + (size_t)b * 3072;
    float r  = 1.f / (1.f + expf(-(gi[h] + gh[h])));
    float z  = 1.f / (1.f + expf(-(gi[1024 + h] + gh[1024 + h])));
    float n  = tanhf(gi[2048 + h] + r * gh[2048 + h]);
    float hp = hid[b * HIDDEN + h];
    float hn = (1.f - z) * n + z * hp;
    hnew_out[b * HIDDEN + h] = hn;
    y_bf[b * 2048 + h] = (__bf16)hn;
}

// In-place log_softmax over vocab per batch row (logits already in d_out)
__global__ void k_logsoftmax(float* __restrict__ logits) {
    int b = blockIdx.x;
    float* row = logits + (size_t)b * VOCAB;
    __shared__ float red[1024];
    int t = threadIdx.x;
    float m = -INFINITY;
    for (int i = t; i < VOCAB; i += 1024) m = fmaxf(m, row[i]);
    red[t] = m; __syncthreads();
    for (int off = 512; off; off >>= 1) { if (t < off) red[t] = fmaxf(red[t], red[t + off]); __syncthreads(); }
    m = red[0]; __syncthreads();
    float s = 0.f;
    for (int i = t; i < VOCAB; i += 1024) s += expf(row[i] - m);
    red[t] = s; __syncthreads();
    for (int off = 512; off; off >>= 1) { if (t < off) red[t] += red[t + off]; __syncthreads(); }
    float lse = m + logf(red[0]);
    for (int i = t; i < VOCAB; i += 1024) row[i] = row[i] - lse;
}

extern "C" void kernel_launch(void* const* d_in, const int* in_sizes, int n_in,
                              void* d_out, int out_size, void* d_ws, size_t ws_size,
                              hipStream_t stream) {
    const int*   last_output = (const int*)  d_in[0];
    const float* last_hidden = (const float*)d_in[1];
    const float* enc         = (const float*)d_in[2];
    const float* embedding   = (const float*)d_in[3];
    const float* attn_W      = (const float*)d_in[4];
    // d_in[5] = attn_b: t-independent -> cancels in softmax
    const float* v           = (const float*)d_in[6];
    const float* W_ih        = (const float*)d_in[7];
    const float* W_hh        = (const float*)d_in[8];
    const float* b_ih        = (const float*)d_in[9];
    const float* b_hh        = (const float*)d_in[10];
    const float* out_W       = (const float*)d_in[11];
    const float* out_b       = (const float*)d_in[12];

    float* out_logp = (float*)d_out;                       // [64][50000]
    float* out_hnew = (float*)d_out + (size_t)BATCH * VOCAB; // [64][1024]

    char* ws = (char*)d_ws;
    float*  u2      = (float*) (ws + 0);          //   4 KB
    float*  scores  = (float*) (ws + 4096);       //  64 KB
    float*  attn    = (float*) (ws + 69632);      //  64 KB
    float*  context = (float*) (ws + 135168);     // 256 KB
    float*  Gi      = (float*) (ws + 397312);     // 768 KB  [64][3072]
    float*  Gh      = (float*) (ws + 1183744);    // 768 KB
    __bf16* x_bf    = (__bf16*)(ws + 1970176);    // 192 KB  [64][1536]
    __bf16* hid_bf  = (__bf16*)(ws + 2166784);    // 128 KB  [64][1024]
    __bf16* y_bf    = (__bf16*)(ws + 2297856);    // 256 KB  [64][2048]

    k_u2        <<<4,    256, 0, stream>>>(attn_W, v, u2);
    k_scores    <<<4096, 256, 0, stream>>>(enc, u2, scores);
    k_softmax   <<<64,   256, 0, stream>>>(scores, attn);
    k_context   <<<64,   256, 0, stream>>>(enc, attn, context);
    k_pack      <<<640,  256, 0, stream>>>(last_output, embedding, context, last_hidden,
                                           x_bf, hid_bf, y_bf);
    k_gemm      <<<192,  256, 0, stream>>>(W_ih, b_ih, x_bf,  Gi, 3072, 1536);
    k_gemm      <<<192,  256, 0, stream>>>(W_hh, b_hh, hid_bf, Gh, 3072, 1024);
    k_combine   <<<256,  256, 0, stream>>>(Gi, Gh, last_hidden, out_hnew, y_bf);
    k_gemm      <<<3125, 256, 0, stream>>>(out_W, out_b, y_bf, out_logp, VOCAB, 2048);
    k_logsoftmax<<<64,  1024, 0, stream>>>(out_logp);
}

// Round 2
// 273.296 us; speedup vs baseline: 1.2433x; 1.2433x over previous
//
#include <hip/hip_runtime.h>
#include <cstddef>

// Sizes
#define VOCAB  50000
#define INPUT  512
#define HIDDEN 1024
#define BATCH  64
#define MAXLEN 256

typedef float  f32x4 __attribute__((ext_vector_type(4)));
typedef __bf16 bf16x8 __attribute__((ext_vector_type(8)));

__device__ __forceinline__ bf16x8 cvt8(float4 a, float4 b) {
    bf16x8 r;
    r[0] = (__bf16)a.x; r[1] = (__bf16)a.y; r[2] = (__bf16)a.z; r[3] = (__bf16)a.w;
    r[4] = (__bf16)b.x; r[5] = (__bf16)b.y; r[6] = (__bf16)b.z; r[7] = (__bf16)b.w;
    return r;
}

// Stage A: partial u2 over 16-row h-slices. Block i: h in [i*16, i*16+16).
// Each thread owns 4 k's (float4); per-row read is 4KB contiguous (coalesced).
__global__ void k_u2_part(const float* __restrict__ attn_W, const float* __restrict__ v,
                          float* __restrict__ u2p) {
    int i = blockIdx.x, tid = threadIdx.x;
    int k4 = tid * 4;
    float4 acc = {0.f, 0.f, 0.f, 0.f};
    int h0 = i * 16;
#pragma unroll
    for (int r = 0; r < 16; ++r) {
        int h = h0 + r;
        float4 w = *(const float4*)(attn_W + (size_t)h * (2 * HIDDEN) + HIDDEN + k4);
        float vv = v[h];
        acc.x += vv * w.x; acc.y += vv * w.y; acc.z += vv * w.z; acc.w += vv * w.w;
    }
    *(float4*)(u2p + (size_t)i * HIDDEN + k4) = acc;
}

// Stage B: u2[k] = sum_i u2p[i][k]
__global__ void k_u2_reduce(const float* __restrict__ u2p, float* __restrict__ u2) {
    int k = blockIdx.x * 256 + threadIdx.x;
    float s = 0.f;
#pragma unroll 8
    for (int i = 0; i < 64; ++i) s += u2p[(size_t)i * HIDDEN + k];
    u2[k] = s;
}

// scores[b,t] = dot(enc[t,b,:], u2)  — one wave per (t,b) row
__global__ void k_scores(const float* __restrict__ enc, const float* __restrict__ u2,
                         float* __restrict__ scores) {
    int wid = threadIdx.x >> 6, lane = threadIdx.x & 63;
    int p = blockIdx.x * 4 + wid;               // p = t*BATCH + b
    const float* row = enc + (size_t)p * HIDDEN;
    float acc = 0.f;
#pragma unroll
    for (int i = 0; i < 4; ++i) {
        float4 e = *(const float4*)(row + lane * 4 + i * 256);
        float4 u = *(const float4*)(u2  + lane * 4 + i * 256);
        acc += e.x * u.x + e.y * u.y + e.z * u.z + e.w * u.w;
    }
#pragma unroll
    for (int off = 32; off; off >>= 1) acc += __shfl_down(acc, off, 64);
    if (lane == 0) {
        int b = p & 63, t = p >> 6;
        scores[b * MAXLEN + t] = acc;
    }
}

// softmax over t (256) per batch row
__global__ void k_softmax(const float* __restrict__ scores, float* __restrict__ attn) {
    int b = blockIdx.x, t = threadIdx.x;
    __shared__ float red[256];
    float s = scores[b * MAXLEN + t];
    red[t] = s; __syncthreads();
    for (int off = 128; off; off >>= 1) { if (t < off) red[t] = fmaxf(red[t], red[t + off]); __syncthreads(); }
    float m = red[0]; __syncthreads();
    float e = expf(s - m);
    red[t] = e; __syncthreads();
    for (int off = 128; off; off >>= 1) { if (t < off) red[t] += red[t + off]; __syncthreads(); }
    attn[b * MAXLEN + t] = e * (1.f / red[0]);
}

// context[b,h] = sum_t attn[b,t]*enc[t,b,h] — 256 blocks: b = bid>>2, h-chunk = bid&3
__global__ void k_context(const float* __restrict__ enc, const float* __restrict__ attn,
                          float* __restrict__ context) {
    int b = blockIdx.x >> 2, hc = blockIdx.x & 3, tid = threadIdx.x;
    __shared__ float a[256];
    a[tid] = attn[b * MAXLEN + tid];
    __syncthreads();
    int h = hc * 256 + tid;
    float acc = 0.f;
#pragma unroll 8
    for (int t = 0; t < MAXLEN; ++t)
        acc += a[t] * enc[((size_t)(t * BATCH + b)) * HIDDEN + h];
    context[b * HIDDEN + h] = acc;
}

// Pack bf16 activation buffers
__global__ void k_pack(const int* __restrict__ last_output, const float* __restrict__ embedding,
                       const float* __restrict__ context, const float* __restrict__ hid,
                       __bf16* __restrict__ x_bf, __bf16* __restrict__ hid_bf,
                       __bf16* __restrict__ y_bf) {
    int idx = blockIdx.x * 256 + threadIdx.x;   // 64*2560 total
    int b = idx / 2560, k = idx % 2560;
    if (k < INPUT) {
        float v = embedding[(size_t)last_output[b] * INPUT + k];
        x_bf[b * 1536 + k] = (__bf16)v;
    } else if (k < 1536) {
        float v = context[b * HIDDEN + (k - INPUT)];
        x_bf[b * 1536 + k] = (__bf16)v;
        y_bf[b * 2048 + (k - INPUT) + HIDDEN] = (__bf16)v;
    } else {
        float v = hid[b * HIDDEN + (k - 1536)];
        hid_bf[b * HIDDEN + (k - 1536)] = (__bf16)v;
    }
}

// Small-M GEMM: out[64,N] = A_bf16[64,K] @ W_f32[N,K]^T + bias.
// Block per 16-col tile; 4 waves split K; LDS reduce. MFMA 16x16x32 bf16.
__global__ __launch_bounds__(256) void k_gemm(const float* __restrict__ W,
                                              const float* __restrict__ bias,
                                              const __bf16* __restrict__ A,
                                              float* __restrict__ out,
                                              int N, int K) {
    int tid = threadIdx.x;
    int wid = tid >> 6, lane = tid & 63;
    int jt = blockIdx.x;
    int j  = jt * 16 + (lane & 15);
    int kg = (lane >> 4) * 8;
    int kchunk = K >> 2;
    int kbeg = wid * kchunk, kend = kbeg + kchunk;
    const float*  wrow = W + (size_t)j * K;
    const __bf16* arow = A + (size_t)(lane & 15) * K;
    f32x4 acc[4] = {};
    for (int k0 = kbeg; k0 < kend; k0 += 32) {
        int kk = k0 + kg;
        float4 w0 = *(const float4*)(wrow + kk);
        float4 w1 = *(const float4*)(wrow + kk + 4);
        bf16x8 bw = cvt8(w0, w1);
#pragma unroll
        for (int mt = 0; mt < 4; ++mt) {
            bf16x8 a = *(const bf16x8*)(arow + (size_t)mt * 16 * K + kk);
            acc[mt] = __builtin_amdgcn_mfma_f32_16x16x32_bf16(a, bw, acc[mt], 0, 0, 0);
        }
    }
    __shared__ float lds[4][1024];
#pragma unroll
    for (int mt = 0; mt < 4; ++mt)
#pragma unroll
        for (int r = 0; r < 4; ++r) {
            int m = mt * 16 + (lane >> 4) * 4 + r;
            lds[wid][m * 16 + (lane & 15)] = acc[mt][r];
        }
    __syncthreads();
#pragma unroll
    for (int o = tid; o < 1024; o += 256) {
        float s = lds[0][o] + lds[1][o] + lds[2][o] + lds[3][o];
        int m = o >> 4, jl = o & 15;
        int jj = jt * 16 + jl;
        out[(size_t)m * N + jj] = s + bias[jj];
    }
}

// GRU combine
__global__ void k_combine(const float* __restrict__ Gi, const float* __restrict__ Gh,
                          const float* __restrict__ hid, float* __restrict__ hnew_out,
                          __bf16* __restrict__ y_bf) {
    int idx = blockIdx.x * 256 + threadIdx.x;   // 64*1024
    int b = idx >> 10, h = idx & 1023;
    const float* gi = Gi + (size_t)b * 3072;
    const float* gh = Gh + (size_t)b * 3072;
    float r  = 1.f / (1.f + expf(-(gi[h] + gh[h])));
    float z  = 1.f / (1.f + expf(-(gi[1024 + h] + gh[1024 + h])));
    float n  = tanhf(gi[2048 + h] + r * gh[2048 + h]);
    float hp = hid[b * HIDDEN + h];
    float hn = (1.f - z) * n + z * hp;
    hnew_out[b * HIDDEN + h] = hn;
    y_bf[b * 2048 + h] = (__bf16)hn;
}

// log-softmax phase 1: per (b, chunk-of-6250) partial max & sumexp, LDS-staged
__global__ __launch_bounds__(256) void k_lse_part(const float* __restrict__ logits,
                                                  float* __restrict__ mw, float* __restrict__ sw) {
    int b = blockIdx.x >> 3, c = blockIdx.x & 7, tid = threadIdx.x;
    const float* row = logits + (size_t)b * VOCAB + c * 6250;
    __shared__ float buf[6250];
    __shared__ float red[256];
    float m = -INFINITY;
    for (int i = tid; i < 6250; i += 256) {
        float x = row[i];
        buf[i] = x;
        m = fmaxf(m, x);
    }
    red[tid] = m; __syncthreads();
    for (int off = 128; off; off >>= 1) { if (tid < off) red[tid] = fmaxf(red[tid], red[tid + off]); __syncthreads(); }
    m = red[0]; __syncthreads();
    float s = 0.f;
    for (int i = tid; i < 6250; i += 256) s += expf(buf[i] - m);
    red[tid] = s; __syncthreads();
    for (int off = 128; off; off >>= 1) { if (tid < off) red[tid] += red[tid + off]; __syncthreads(); }
    if (tid == 0) { mw[b * 8 + c] = m; sw[b * 8 + c] = red[0]; }
}

// log-softmax phase 2: combine 8 chunk partials per row -> lse[b]
__global__ void k_lse_combine(const float* __restrict__ mw, const float* __restrict__ sw,
                              float* __restrict__ lse) {
    int b = threadIdx.x;   // 64 threads
    float m = -INFINITY;
#pragma unroll
    for (int c = 0; c < 8; ++c) m = fmaxf(m, mw[b * 8 + c]);
    float s = 0.f;
#pragma unroll
    for (int c = 0; c < 8; ++c) s += sw[b * 8 + c] * expf(mw[b * 8 + c] - m);
    lse[b] = m + logf(s);
}

// log-softmax phase 3: in-place subtract (float4 grid-stride; 50000 % 4 == 0)
__global__ void k_lse_sub(float* __restrict__ logits, const float* __restrict__ lse) {
    int idx = blockIdx.x * 256 + threadIdx.x;   // 800000 float4s
    size_t f = (size_t)idx * 4;
    int b = (int)(f / VOCAB);
    float l = lse[b];
    float4 x = *(float4*)(logits + f);
    x.x -= l; x.y -= l; x.z -= l; x.w -= l;
    *(float4*)(logits + f) = x;
}

extern "C" void kernel_launch(void* const* d_in, const int* in_sizes, int n_in,
                              void* d_out, int out_size, void* d_ws, size_t ws_size,
                              hipStream_t stream) {
    const int*   last_output = (const int*)  d_in[0];
    const float* last_hidden = (const float*)d_in[1];
    const float* enc         = (const float*)d_in[2];
    const float* embedding   = (const float*)d_in[3];
    const float* attn_W      = (const float*)d_in[4];
    // d_in[5] = attn_b: t-independent -> cancels in softmax
    const float* v           = (const float*)d_in[6];
    const float* W_ih        = (const float*)d_in[7];
    const float* W_hh        = (const float*)d_in[8];
    const float* b_ih        = (const float*)d_in[9];
    const float* b_hh        = (const float*)d_in[10];
    const float* out_W       = (const float*)d_in[11];
    const float* out_b       = (const float*)d_in[12];

    float* out_logp = (float*)d_out;                         // [64][50000]
    float* out_hnew = (float*)d_out + (size_t)BATCH * VOCAB; // [64][1024]

    char* ws = (char*)d_ws;
    float*  u2p     = (float*) (ws + 0);          // 256 KB [64][1024]
    float*  u2      = (float*) (ws + 262144);     //   4 KB
    float*  scores  = (float*) (ws + 266240);     //  64 KB
    float*  attn    = (float*) (ws + 331776);     //  64 KB
    float*  context = (float*) (ws + 397312);     // 256 KB
    float*  Gi      = (float*) (ws + 659456);     // 768 KB [64][3072]
    float*  Gh      = (float*) (ws + 1445888);    // 768 KB
    __bf16* x_bf    = (__bf16*)(ws + 2232320);    // 192 KB [64][1536]
    __bf16* hid_bf  = (__bf16*)(ws + 2428928);    // 128 KB [64][1024]
    __bf16* y_bf    = (__bf16*)(ws + 2560000);    // 256 KB [64][2048]
    float*  mw      = (float*) (ws + 2822144);    //   2 KB [64][8]
    float*  sw      = (float*) (ws + 2824192);    //   2 KB
    float*  lse     = (float*) (ws + 2826240);    // 256 B

    k_u2_part   <<<64,   256, 0, stream>>>(attn_W, v, u2p);
    k_u2_reduce <<<4,    256, 0, stream>>>(u2p, u2);
    k_scores    <<<4096, 256, 0, stream>>>(enc, u2, scores);
    k_softmax   <<<64,   256, 0, stream>>>(scores, attn);
    k_context   <<<256,  256, 0, stream>>>(enc, attn, context);
    k_pack      <<<640,  256, 0, stream>>>(last_output, embedding, context, last_hidden,
                                           x_bf, hid_bf, y_bf);
    k_gemm      <<<192,  256, 0, stream>>>(W_ih, b_ih, x_bf,  Gi, 3072, 1536);
    k_gemm      <<<192,  256, 0, stream>>>(W_hh, b_hh, hid_bf, Gh, 3072, 1024);
    k_combine   <<<256,  256, 0, stream>>>(Gi, Gh, last_hidden, out_hnew, y_bf);
    k_gemm      <<<3125, 256, 0, stream>>>(out_W, out_b, y_bf, out_logp, VOCAB, 2048);
    k_lse_part  <<<512,  256, 0, stream>>>(out_logp, mw, sw);
    k_lse_combine<<<1,    64, 0, stream>>>(mw, sw, lse);
    k_lse_sub   <<<3125, 256, 0, stream>>>(out_logp, lse);
}

// Round 3
// 220.840 us; speedup vs baseline: 1.5386x; 1.2375x over previous
//
#include <hip/hip_runtime.h>
#include <cstddef>

#define VOCAB  50000
#define INPUT  512
#define HIDDEN 1024
#define BATCH  64
#define MAXLEN 256
#define NTILE  3125   // 16-col tiles over VOCAB

typedef float  f32x4 __attribute__((ext_vector_type(4)));
typedef __bf16 bf16x8 __attribute__((ext_vector_type(8)));

__device__ __forceinline__ bf16x8 cvt8(float4 a, float4 b) {
    bf16x8 r;
    r[0] = (__bf16)a.x; r[1] = (__bf16)a.y; r[2] = (__bf16)a.z; r[3] = (__bf16)a.w;
    r[4] = (__bf16)b.x; r[5] = (__bf16)b.y; r[6] = (__bf16)b.z; r[7] = (__bf16)b.w;
    return r;
}

// u2[k] = sum_h v[h] * attn_W[h, HIDDEN+k].  16 blocks; block i owns k in [i*64,i*64+64).
// Thread t: k = i*64 + (t&63), h-range = (t>>6)*256..+256. Coalesced 256B row segments.
__global__ void k_u2(const float* __restrict__ attn_W, const float* __restrict__ v,
                     float* __restrict__ u2) {
    int tid = threadIdx.x;
    int kk = blockIdx.x * 64 + (tid & 63);
    int hg = tid >> 6;
    float acc = 0.f;
#pragma unroll 8
    for (int h = hg * 256; h < hg * 256 + 256; ++h)
        acc += v[h] * attn_W[(size_t)h * (2 * HIDDEN) + HIDDEN + kk];
    __shared__ float red[4][64];
    red[hg][tid & 63] = acc;
    __syncthreads();
    if (tid < 64)
        u2[blockIdx.x * 64 + tid] = red[0][tid] + red[1][tid] + red[2][tid] + red[3][tid];
}

// blocks <4096: scores[b,t] = dot(enc[t,b,:], u2), one wave per (t,b).
// blocks >=4096: pack emb -> x_bf[:, :512] and last_hidden -> hid_bf (bf16).
__global__ void k_scores_pack(const float* __restrict__ enc, const float* __restrict__ u2,
                              float* __restrict__ scores,
                              const int* __restrict__ last_output,
                              const float* __restrict__ embedding,
                              const float* __restrict__ hid,
                              __bf16* __restrict__ x_bf, __bf16* __restrict__ hid_bf) {
    int bid = blockIdx.x, tid = threadIdx.x;
    if (bid < 4096) {
        int wid = tid >> 6, lane = tid & 63;
        int p = bid * 4 + wid;               // p = t*BATCH + b
        const float* row = enc + (size_t)p * HIDDEN;
        float acc = 0.f;
#pragma unroll
        for (int i = 0; i < 4; ++i) {
            float4 e = *(const float4*)(row + lane * 4 + i * 256);
            float4 u = *(const float4*)(u2  + lane * 4 + i * 256);
            acc += e.x * u.x + e.y * u.y + e.z * u.z + e.w * u.w;
        }
#pragma unroll
        for (int off = 32; off; off >>= 1) acc += __shfl_down(acc, off, 64);
        if (lane == 0) scores[(p & 63) * MAXLEN + (p >> 6)] = acc;
    } else {
        int idx = (bid - 4096) * 256 + tid;  // 98304 total
        if (idx < 64 * INPUT) {
            int b = idx >> 9, k = idx & 511;
            x_bf[b * 1536 + k] = (__bf16)embedding[(size_t)last_output[b] * INPUT + k];
        } else {
            idx -= 64 * INPUT;
            int b = idx >> 10, h = idx & 1023;
            hid_bf[b * HIDDEN + h] = (__bf16)hid[b * HIDDEN + h];
        }
    }
}

// Fused softmax + context + bf16 pack. 256 blocks: b = bid>>2, h-chunk = bid&3.
__global__ void k_ctx(const float* __restrict__ enc, const float* __restrict__ scores,
                      __bf16* __restrict__ x_bf, __bf16* __restrict__ y_bf) {
    int b = blockIdx.x >> 2, hc = blockIdx.x & 3, tid = threadIdx.x;
    __shared__ float a[256];
    __shared__ float red[256];
    float s = scores[b * MAXLEN + tid];
    red[tid] = s; __syncthreads();
    for (int off = 128; off; off >>= 1) { if (tid < off) red[tid] = fmaxf(red[tid], red[tid + off]); __syncthreads(); }
    float m = red[0]; __syncthreads();
    float e = expf(s - m);
    red[tid] = e; __syncthreads();
    for (int off = 128; off; off >>= 1) { if (tid < off) red[tid] += red[tid + off]; __syncthreads(); }
    a[tid] = e * (1.f / red[0]);
    __syncthreads();
    int h = hc * 256 + tid;
    float acc = 0.f;
#pragma unroll 8
    for (int t = 0; t < MAXLEN; ++t)
        acc += a[t] * enc[((size_t)(t * BATCH + b)) * HIDDEN + h];
    x_bf[b * 1536 + INPUT + h]   = (__bf16)acc;
    y_bf[b * 2048 + HIDDEN + h]  = (__bf16)acc;
}

// Small-M GEMM tile body: out[64,N] tile jt (16 cols) = A[64,K] @ W[N,K]^T + bias.
__device__ __forceinline__ void gemm_tile(const float* __restrict__ W,
                                          const float* __restrict__ bias,
                                          const __bf16* __restrict__ A,
                                          float* __restrict__ out,
                                          int N, int K, int jt, int tid) {
    int wid = tid >> 6, lane = tid & 63;
    int j  = jt * 16 + (lane & 15);
    int kg = (lane >> 4) * 8;
    int kchunk = K >> 2;
    int kbeg = wid * kchunk, kend = kbeg + kchunk;
    const float*  wrow = W + (size_t)j * K;
    const __bf16* arow = A + (size_t)(lane & 15) * K;
    f32x4 acc[4] = {};
    for (int k0 = kbeg; k0 < kend; k0 += 32) {
        int kk = k0 + kg;
        float4 w0 = *(const float4*)(wrow + kk);
        float4 w1 = *(const float4*)(wrow + kk + 4);
        bf16x8 bw = cvt8(w0, w1);
#pragma unroll
        for (int mt = 0; mt < 4; ++mt) {
            bf16x8 av = *(const bf16x8*)(arow + (size_t)mt * 16 * K + kk);
            acc[mt] = __builtin_amdgcn_mfma_f32_16x16x32_bf16(av, bw, acc[mt], 0, 0, 0);
        }
    }
    __shared__ float lds[4][1024];
#pragma unroll
    for (int mt = 0; mt < 4; ++mt)
#pragma unroll
        for (int r = 0; r < 4; ++r) {
            int m = mt * 16 + (lane >> 4) * 4 + r;
            lds[wid][m * 16 + (lane & 15)] = acc[mt][r];
        }
    __syncthreads();
#pragma unroll
    for (int o = tid; o < 1024; o += 256) {
        float s = lds[0][o] + lds[1][o] + lds[2][o] + lds[3][o];
        int m = o >> 4, jl = o & 15;
        int jj = jt * 16 + jl;
        out[(size_t)m * N + jj] = s + bias[jj];
    }
}

// GRU gate GEMMs, one dispatch: blocks 0..191 -> Gi (K=1536), 192..383 -> Gh (K=1024)
__global__ __launch_bounds__(256) void k_gemm_gru(const float* __restrict__ W_ih,
                                                  const float* __restrict__ b_ih,
                                                  const __bf16* __restrict__ x_bf,
                                                  float* __restrict__ Gi,
                                                  const float* __restrict__ W_hh,
                                                  const float* __restrict__ b_hh,
                                                  const __bf16* __restrict__ hid_bf,
                                                  float* __restrict__ Gh) {
    int bid = blockIdx.x, tid = threadIdx.x;
    if (bid < 192) gemm_tile(W_ih, b_ih, x_bf,  Gi, 3072, 1536, bid,       tid);
    else           gemm_tile(W_hh, b_hh, hid_bf, Gh, 3072, 1024, bid - 192, tid);
}

// GRU combine: h_new = (1-z)*n + z*h_prev
__global__ void k_combine(const float* __restrict__ Gi, const float* __restrict__ Gh,
                          const float* __restrict__ hid, float* __restrict__ hnew_out,
                          __bf16* __restrict__ y_bf) {
    int idx = blockIdx.x * 256 + threadIdx.x;   // 64*1024
    int b = idx >> 10, h = idx & 1023;
    const float* gi = Gi + (size_t)b * 3072;
    const float* gh = Gh + (size_t)b * 3072;
    float r  = 1.f / (1.f + expf(-(gi[h] + gh[h])));
    float z  = 1.f / (1.f + expf(-(gi[1024 + h] + gh[1024 + h])));
    float n  = tanhf(gi[2048 + h] + r * gh[2048 + h]);
    float hp = hid[b * HIDDEN + h];
    float hn = (1.f - z) * n + z * hp;
    hnew_out[b * HIDDEN + h] = hn;
    y_bf[b * 2048 + h] = (__bf16)hn;
}

// Vocab projection: 1563 blocks, 2 x 16-col tiles each (last block: 1 tile).
// Epilogue also emits per-tile log-softmax partials (row max + sumexp) to mw/sw.
__global__ __launch_bounds__(256) void k_gemv(const float* __restrict__ W,
                                              const float* __restrict__ bias,
                                              const __bf16* __restrict__ A,
                                              float* __restrict__ out,
                                              float* __restrict__ mw,
                                              float* __restrict__ sw) {
    int bid = blockIdx.x, tid = threadIdx.x;
    int wid = tid >> 6, lane = tid & 63;
    int kg = (lane >> 4) * 8;
    int kbeg = wid * 512, kend = kbeg + 512;     // K=2048 split over 4 waves
    int ntiles = (bid == 1562) ? 1 : 2;
    int j0 = bid * 32 + (lane & 15);
    int jr0 = min(j0,      VOCAB - 1);
    int jr1 = min(j0 + 16, VOCAB - 1);
    const float*  wrow0 = W + (size_t)jr0 * 2048;
    const float*  wrow1 = W + (size_t)jr1 * 2048;
    const __bf16* arow  = A + (size_t)(lane & 15) * 2048;
    f32x4 acc[2][4] = {};
    for (int k0 = kbeg; k0 < kend; k0 += 32) {
        int kk = k0 + kg;
        float4 p0 = *(const float4*)(wrow0 + kk);
        float4 p1 = *(const float4*)(wrow0 + kk + 4);
        float4 q0 = *(const float4*)(wrow1 + kk);
        float4 q1 = *(const float4*)(wrow1 + kk + 4);
        bf16x8 bw0 = cvt8(p0, p1);
        bf16x8 bw1 = cvt8(q0, q1);
#pragma unroll
        for (int mt = 0; mt < 4; ++mt) {
            bf16x8 av = *(const bf16x8*)(arow + (size_t)mt * 16 * 2048 + kk);
            acc[0][mt] = __builtin_amdgcn_mfma_f32_16x16x32_bf16(av, bw0, acc[0][mt], 0, 0, 0);
            acc[1][mt] = __builtin_amdgcn_mfma_f32_16x16x32_bf16(av, bw1, acc[1][mt], 0, 0, 0);
        }
    }
    __shared__ float lds[4][1024];
    for (int u = 0; u < ntiles; ++u) {
        if (u) __syncthreads();                  // protect lds reuse
#pragma unroll
        for (int mt = 0; mt < 4; ++mt)
#pragma unroll
            for (int r = 0; r < 4; ++r) {
                int m = mt * 16 + (lane >> 4) * 4 + r;
                lds[wid][m * 16 + (lane & 15)] = acc[u][mt][r];
            }
        __syncthreads();
#pragma unroll
        for (int o = tid; o < 1024; o += 256) {
            float s = lds[0][o] + lds[1][o] + lds[2][o] + lds[3][o];
            int m = o >> 4, jl = o & 15;
            int jj = bid * 32 + u * 16 + jl;
            s += bias[jj];
            out[(size_t)m * VOCAB + jj] = s;
            lds[0][o] = s;                       // safe: each o owned by one thread
        }
        __syncthreads();
        if (tid < 64) {
            int m = tid;
            float mx = -INFINITY;
#pragma unroll
            for (int jl = 0; jl < 16; ++jl) mx = fmaxf(mx, lds[0][m * 16 + jl]);
            float se = 0.f;
#pragma unroll
            for (int jl = 0; jl < 16; ++jl) se += expf(lds[0][m * 16 + jl] - mx);
            int tile = bid * 2 + u;
            mw[(size_t)m * NTILE + tile] = mx;
            sw[(size_t)m * NTILE + tile] = se;
        }
    }
}

// Combine 3125 per-tile partials per row -> lse[b]. One block per row.
__global__ void k_lse_combine(const float* __restrict__ mw, const float* __restrict__ sw,
                              float* __restrict__ lse) {
    int b = blockIdx.x, tid = threadIdx.x;
    __shared__ float red[256];
    const float* mrow = mw + (size_t)b * NTILE;
    const float* srow = sw + (size_t)b * NTILE;
    float m = -INFINITY;
    for (int i = tid; i < NTILE; i += 256) m = fmaxf(m, mrow[i]);
    red[tid] = m; __syncthreads();
    for (int off = 128; off; off >>= 1) { if (tid < off) red[tid] = fmaxf(red[tid], red[tid + off]); __syncthreads(); }
    m = red[0]; __syncthreads();
    float s = 0.f;
    for (int i = tid; i < NTILE; i += 256) s += srow[i] * expf(mrow[i] - m);
    red[tid] = s; __syncthreads();
    for (int off = 128; off; off >>= 1) { if (tid < off) red[tid] += red[tid + off]; __syncthreads(); }
    if (tid == 0) lse[b] = m + logf(red[0]);
}

// In-place subtract lse (float4; rows are 4-aligned since 50000 % 4 == 0)
__global__ void k_lse_sub(float* __restrict__ logits, const float* __restrict__ lse) {
    int idx = blockIdx.x * 256 + threadIdx.x;   // 800000 float4s
    size_t f = (size_t)idx * 4;
    float l = lse[(int)(f / VOCAB)];
    float4 x = *(float4*)(logits + f);
    x.x -= l; x.y -= l; x.z -= l; x.w -= l;
    *(float4*)(logits + f) = x;
}

extern "C" void kernel_launch(void* const* d_in, const int* in_sizes, int n_in,
                              void* d_out, int out_size, void* d_ws, size_t ws_size,
                              hipStream_t stream) {
    const int*   last_output = (const int*)  d_in[0];
    const float* last_hidden = (const float*)d_in[1];
    const float* enc         = (const float*)d_in[2];
    const float* embedding   = (const float*)d_in[3];
    const float* attn_W      = (const float*)d_in[4];
    // d_in[5] = attn_b: t-independent -> cancels in softmax
    const float* v           = (const float*)d_in[6];
    const float* W_ih        = (const float*)d_in[7];
    const float* W_hh        = (const float*)d_in[8];
    const float* b_ih        = (const float*)d_in[9];
    const float* b_hh        = (const float*)d_in[10];
    const float* out_W       = (const float*)d_in[11];
    const float* out_b       = (const float*)d_in[12];

    float* out_logp = (float*)d_out;                         // [64][50000]
    float* out_hnew = (float*)d_out + (size_t)BATCH * VOCAB; // [64][1024]

    char* ws = (char*)d_ws;
    float*  u2      = (float*) (ws + 0);          //   4 KB
    float*  scores  = (float*) (ws + 4096);       //  64 KB
    __bf16* x_bf    = (__bf16*)(ws + 69632);      // 192 KB [64][1536]
    __bf16* hid_bf  = (__bf16*)(ws + 266240);     // 128 KB [64][1024]
    __bf16* y_bf    = (__bf16*)(ws + 397312);     // 256 KB [64][2048]
    float*  Gi      = (float*) (ws + 659456);     // 768 KB [64][3072]
    float*  Gh      = (float*) (ws + 1445888);    // 768 KB
    float*  mw      = (float*) (ws + 2232320);    // 800 KB [64][3125]
    float*  sw      = (float*) (ws + 3032320);    // 800 KB
    float*  lse     = (float*) (ws + 3832320);    // 256 B

    k_u2          <<<16,   256, 0, stream>>>(attn_W, v, u2);
    k_scores_pack <<<4480, 256, 0, stream>>>(enc, u2, scores, last_output, embedding,
                                             last_hidden, x_bf, hid_bf);
    k_ctx         <<<256,  256, 0, stream>>>(enc, scores, x_bf, y_bf);
    k_gemm_gru    <<<384,  256, 0, stream>>>(W_ih, b_ih, x_bf, Gi, W_hh, b_hh, hid_bf, Gh);
    k_combine     <<<256,  256, 0, stream>>>(Gi, Gh, last_hidden, out_hnew, y_bf);
    k_gemv        <<<1563, 256, 0, stream>>>(out_W, out_b, y_bf, out_logp, mw, sw);
    k_lse_combine <<<64,   256, 0, stream>>>(mw, sw, lse);
    k_lse_sub     <<<3125, 256, 0, stream>>>(out_logp, lse);
}